// Round 18
// baseline (777.979 us; speedup 1.0000x reference)
//
#include <hip/hip_runtime.h>
#include <math.h>

// Problem constants
#define N_TOK 16384   // B*S
#define DDIM  768
#define HDIM  512
#define KCB   4096

// d_out float offsets (outputs concatenated: quantized_st, loss, perplexity, idx, enc)
#define Q_OFF    0L
#define LOSS_OFF 12582912L
#define PERP_OFF 12582913L
#define IDX_OFF  12582914L
#define ENC_OFF  12599298L

#define MARGIN_AB 4.0e-3f   // hard bound: bf16 rel err 2^-9 -> dot err <= 2*2^-9 = 3.9e-3
#define CAND_CAP 128

// screen geometry (R10-proven): BM=64 rows, 2048 codes/block (8 chunks x 256), BK=32
#define CODES_PER 2048

// hgemm (R5-proven): 128x128 tile, BK=32. K' = 2304 virtual (Ah@Wh | Al@Wh | Ah@Wl)
#define BMT 128
#define BNT 128
#define KS 1536
#define HSTEPS (2304 / 32)   // 72

typedef short    bf16x8 __attribute__((ext_vector_type(8)));
typedef _Float16 half8  __attribute__((ext_vector_type(8)));
typedef float    f32x4  __attribute__((ext_vector_type(4)));

__device__ __forceinline__ void gload_lds16(const void* g, void* l) {
  __builtin_amdgcn_global_load_lds((const __attribute__((address_space(1))) void*)g,
                                   (__attribute__((address_space(3))) void*)l, 16, 0, 0);
}

__device__ __forceinline__ unsigned short f2bf(float f) {  // RNE f32 -> bf16
  unsigned u = __float_as_uint(f);
  return (unsigned short)((u + 0x7fffu + ((u >> 16) & 1u)) >> 16);
}

#define VMCNT10 asm volatile("s_waitcnt vmcnt(10)" ::: "memory")
#define VMCNT5  asm volatile("s_waitcnt vmcnt(5)" ::: "memory")
#define VMCNT0  asm volatile("s_waitcnt vmcnt(0)" ::: "memory")
#define BARRIER asm volatile("s_barrier" ::: "memory")

// ---------------------------------------------------------------------------
// fused prep: init + all 4 hi/lo splits (R12-proven).
__global__ __launch_bounds__(256) void k_prep(const float* __restrict__ x,
                                              const float* __restrict__ cb,
                                              const float* __restrict__ w_in,
                                              const float* __restrict__ w_code,
                                              _Float16* __restrict__ x2,
                                              _Float16* __restrict__ cb2,
                                              _Float16* __restrict__ win2,
                                              _Float16* __restrict__ wcode2,
                                              int* __restrict__ hist,
                                              float* __restrict__ sums,
                                              int* __restrict__ g_cnt) {
  const long u = (long)blockIdx.x * 256 + threadIdx.x;
  if (u < 16448) {  // init lane
    const int g = (int)u;
    if (g < N_TOK) g_cnt[g] = 0;
    if (g < KCB)  hist[g] = 0;
    if (g < 8)    sums[g] = 0.0f;
  }
  const float* src; _Float16* dst; long n;
  long v = u;
  if (v < (long)N_TOK * 96)                           { src = x;      dst = x2;     n = v / 96; }
  else if ((v -= (long)N_TOK * 96) < (long)KCB * 96)  { src = cb;     dst = cb2;    n = v / 96; }
  else if ((v -= (long)KCB * 96) < 512L * 96)         { src = w_in;   dst = win2;   n = v / 96; }
  else if ((v -= 512L * 96) < 512L * 96)              { src = w_code; dst = wcode2; n = v / 96; }
  else return;
  const int c0 = ((int)(v % 96)) * 8;
  const float4 v0 = *(const float4*)&src[n * DDIM + c0];
  const float4 v1 = *(const float4*)&src[n * DDIM + c0 + 4];
  const float f[8] = {v0.x, v0.y, v0.z, v0.w, v1.x, v1.y, v1.z, v1.w};
  half8 hv, lv;
#pragma unroll
  for (int j = 0; j < 8; ++j) {
    const _Float16 h = (_Float16)f[j];
    hv[j] = h;
    lv[j] = (_Float16)(f[j] - (float)h);
  }
  *(half8*)&dst[n * KS + c0]       = hv;
  *(half8*)&dst[n * KS + 768 + c0] = lv;
}

// ---------------------------------------------------------------------------
// fp16 split MFMA GEMM (R5-proven): 128x128 tile, BK=32, dbuf linear LDS.
// bx < 128 -> x rows; else codebook rows.
__global__ __launch_bounds__(256) void k_hgemm(const _Float16* __restrict__ x2,
                                               const _Float16* __restrict__ cb2,
                                               const _Float16* __restrict__ win2,
                                               const _Float16* __restrict__ wcode2,
                                               const float* __restrict__ b_in,
                                               const float* __restrict__ b_code,
                                               float* __restrict__ latin,
                                               float* __restrict__ latcb) {
  __shared__ __align__(16) _Float16 A_lds[2][BMT][32];
  __shared__ __align__(16) _Float16 B_lds[2][BNT][32];

  const int tid = threadIdx.x;
  const int lane = tid & 63;
  const int w = tid >> 6;
  const int wr = w >> 1, wc = w & 1;   // wave quadrant: 64x64
  const int arow = lane & 15;
  const int kseg = lane >> 4;          // 0..3
  const int rgrp = (lane >> 4) * 4;
  const int bx = blockIdx.x;
  const int col0 = blockIdx.y * BNT;

  const _Float16* Ap; const float* biasp; float* outp; int row0;
  if (bx < 128) { Ap = x2;  biasp = b_in;   outp = latin; row0 = bx * BMT; }
  else          { Ap = cb2; biasp = b_code; outp = latcb; row0 = (bx - 128) * BMT; }
  const _Float16* Bp = (bx < 128) ? win2 : wcode2;

  f32x4 acc[4][4];
#pragma unroll
  for (int mi = 0; mi < 4; ++mi)
#pragma unroll
    for (int nj = 0; nj < 4; ++nj)
#pragma unroll
      for (int r = 0; r < 4; ++r) acc[mi][nj][r] = 0.0f;

#define HSTAGE(s_, b_)                                                         \
  do {                                                                         \
    const int kel_ = (s_) * 32;                                                \
    const int kA_ = (kel_ < KS) ? kel_ : (kel_ - KS);                          \
    const int kB_ = (kel_ < 768) ? kel_ : (kel_ - 768);                        \
    _Pragma("unroll")                                                          \
    for (int i_ = 0; i_ < 2; ++i_) {                                           \
      const int v_ = tid + i_ * 256;                                           \
      const int r_ = v_ >> 2, sg_ = v_ & 3;                                    \
      gload_lds16(&Ap[(long)(row0 + r_) * KS + kA_ + sg_ * 8],                 \
                  (char*)&A_lds[b_][0][0] + (size_t)v_ * 16);                  \
    }                                                                          \
    _Pragma("unroll")                                                          \
    for (int i_ = 0; i_ < 2; ++i_) {                                           \
      const int v_ = tid + i_ * 256;                                           \
      const int r_ = v_ >> 2, sg_ = v_ & 3;                                    \
      gload_lds16(&Bp[(long)(col0 + r_) * KS + kB_ + sg_ * 8],                 \
                  (char*)&B_lds[b_][0][0] + (size_t)v_ * 16);                  \
    }                                                                          \
  } while (0)

  HSTAGE(0, 0);
  __syncthreads();

  for (int s = 0; s < HSTEPS; ++s) {
    const int b = s & 1;
    if (s + 1 < HSTEPS) HSTAGE(s + 1, b ^ 1);
    half8 af[4], bfr[4];
#pragma unroll
    for (int mi = 0; mi < 4; ++mi)
      af[mi] = *(const half8*)&A_lds[b][wr * 64 + mi * 16 + arow][kseg * 8];
#pragma unroll
    for (int nj = 0; nj < 4; ++nj)
      bfr[nj] = *(const half8*)&B_lds[b][wc * 64 + nj * 16 + arow][kseg * 8];
#pragma unroll
    for (int mi = 0; mi < 4; ++mi)
#pragma unroll
      for (int nj = 0; nj < 4; ++nj)
        acc[mi][nj] = __builtin_amdgcn_mfma_f32_16x16x32_f16(af[mi], bfr[nj], acc[mi][nj], 0, 0, 0);
    __syncthreads();
  }
#undef HSTAGE

#pragma unroll
  for (int nj = 0; nj < 4; ++nj) {
    const int ocol = col0 + wc * 64 + nj * 16 + arow;
    const float bv = biasp[ocol];
#pragma unroll
    for (int mi = 0; mi < 4; ++mi)
#pragma unroll
      for (int r = 0; r < 4; ++r) {
        const int orow = row0 + wr * 64 + mi * 16 + rgrp + r;
        outp[(long)orow * HDIM + ocol] = acc[mi][nj][r] + bv;
      }
  }
}

// ---------------------------------------------------------------------------
// fused rownorm (R12-proven): 4 rows/block. row < 4096 -> latcb, else latin.
__global__ __launch_bounds__(256) void k_rownorm2(const float* __restrict__ latcb,
                                                  const float* __restrict__ latin,
                                                  float* __restrict__ inv_b,
                                                  float* __restrict__ b2,
                                                  float* __restrict__ inv_a,
                                                  float* __restrict__ a2,
                                                  unsigned short* __restrict__ latcb_bf,
                                                  unsigned short* __restrict__ latin_bf) {
  const int grow = blockIdx.x * 4 + (threadIdx.x >> 6);
  const int lane = threadIdx.x & 63;
  const float* raw; float* inv; float* n2; unsigned short* nbf; int row;
  if (grow < KCB) { raw = latcb; inv = inv_b; n2 = b2; nbf = latcb_bf; row = grow; }
  else            { raw = latin; inv = inv_a; n2 = a2; nbf = latin_bf; row = grow - KCB; }
  const float4 v0 = *(const float4*)&raw[(long)row * HDIM + lane * 8];
  const float4 v1 = *(const float4*)&raw[(long)row * HDIM + lane * 8 + 4];
  float s = v0.x * v0.x + v0.y * v0.y + v0.z * v0.z + v0.w * v0.w
          + v1.x * v1.x + v1.y * v1.y + v1.z * v1.z + v1.w * v1.w;
#pragma unroll
  for (int o = 32; o; o >>= 1) s += __shfl_xor(s, o);
  const float iv = 1.0f / sqrtf(s + 1e-6f);
  float t[8];
  t[0] = v0.x * iv; t[1] = v0.y * iv; t[2] = v0.z * iv; t[3] = v0.w * iv;
  t[4] = v1.x * iv; t[5] = v1.y * iv; t[6] = v1.z * iv; t[7] = v1.w * iv;
  float s2 = 0.0f;
#pragma unroll
  for (int j = 0; j < 8; ++j) s2 += t[j] * t[j];
#pragma unroll
  for (int o = 32; o; o >>= 1) s2 += __shfl_xor(s2, o);
  bf16x8 pk;
#pragma unroll
  for (int j = 0; j < 8; ++j) pk[j] = (short)f2bf(t[j]);
  *(bf16x8*)&nbf[(long)row * HDIM + lane * 8] = pk;
  if (lane == 0) { inv[row] = iv; n2[row] = s2; }
}

// ---------------------------------------------------------------------------
// bf16 MFMA screening (R17-proven): R10 schedule + fused enc zero-fill
// (one nt-store per thread per K-step, hidden under the MFMA pipeline).
__global__ __launch_bounds__(256) void k_screen(const unsigned short* __restrict__ Abf,
                                                const unsigned short* __restrict__ Bbf,
                                                int* __restrict__ g_cnt,
                                                int* __restrict__ g_cand,
                                                f32x4* __restrict__ encz) {
  __shared__ __align__(16) unsigned short A_lds[4][64][32];    // 16 KB
  __shared__ __align__(16) unsigned short B_lds[4][256][32];   // 64 KB

  const int tid = threadIdx.x;
  const int lane = tid & 63;
  const int w = tid >> 6;
  const int wr = w >> 1, wc = w & 1;   // wave tile: 32 rows x 128 codes
  const int arow = lane & 15;
  const int kseg = lane >> 4;          // 0..3
  const int rgrp = kseg * 4;
  const int row0 = blockIdx.x * 64;
  const int csplit = blockIdx.y * CODES_PER;

  // enc zero-fill slice: flat block id * 32768 f32x4 (512KB), 256/step
  f32x4* encp = encz + ((long)(blockIdx.y * (N_TOK / 64) + blockIdx.x)) * 32768 + tid;
  const f32x4 z4 = {0.0f, 0.0f, 0.0f, 0.0f};
#define ZSTORE(sid_) __builtin_nontemporal_store(z4, encp + (sid_) * 256)

  // staging source pointers (seg pre-swizzled: seg_g = seg ^ ((row>>1)&3))
  const int ar = tid >> 2;
  const int aseg = (tid & 3) ^ ((ar >> 1) & 3);
  const unsigned short* gA = Abf + (long)(row0 + ar) * HDIM + aseg * 8;
  const unsigned short* gB[4];
#pragma unroll
  for (int i = 0; i < 4; ++i) {
    const int u = tid + i * 256;
    const int br = u >> 2;
    const int bseg = (u & 3) ^ ((br >> 1) & 3);
    gB[i] = Bbf + (long)(csplit + br) * HDIM + bseg * 8;
  }

  // swizzled LDS frag-read base pointers
  const int q = (arow >> 1) & 3;
  const int ss = (kseg ^ q) * 16;
  const char* pAf = (const char*)&A_lds[0][0][0] + (wr * 32 + arow) * 64 + ss;
  const char* pBf = (const char*)&B_lds[0][0][0] + (wc * 128 + arow) * 64 + ss;

  f32x4 acc[2][8];
#pragma unroll
  for (int mi = 0; mi < 2; ++mi)
#pragma unroll
    for (int nj = 0; nj < 8; ++nj)
#pragma unroll
      for (int r = 0; r < 4; ++r) acc[mi][nj][r] = 0.0f;

  float runmax[8];
#pragma unroll
  for (int i = 0; i < 8; ++i) runmax[i] = -3.0e38f;

#define STAGE(kk_, buf_, CADD_)                                                \
  { gload_lds16(gA + (kk_) * 32,                                               \
                (char*)&A_lds[0][0][0] + (buf_) * 4096 + (size_t)tid * 16);    \
    _Pragma("unroll")                                                          \
    for (int i_ = 0; i_ < 4; ++i_)                                             \
      gload_lds16(gB[i_] + (CADD_) + (kk_) * 32,                               \
                  (char*)&B_lds[0][0][0] + (buf_) * 16384 +                    \
                  (size_t)(tid + i_ * 256) * 16); }

#define COMPUTE(buf_)                                                          \
  { bf16x8 af[2], bfr[8];                                                      \
    af[0] = *(const bf16x8*)(pAf + (buf_) * 4096);                             \
    af[1] = *(const bf16x8*)(pAf + (buf_) * 4096 + 1024);                      \
    _Pragma("unroll")                                                          \
    for (int nj = 0; nj < 8; ++nj)                                             \
      bfr[nj] = *(const bf16x8*)(pBf + (buf_) * 16384 + nj * 1024);            \
    _Pragma("unroll")                                                          \
    for (int mi = 0; mi < 2; ++mi)                                             \
      _Pragma("unroll")                                                        \
      for (int nj = 0; nj < 8; ++nj)                                           \
        acc[mi][nj] = __builtin_amdgcn_mfma_f32_16x16x32_bf16(af[mi], bfr[nj], \
                                                              acc[mi][nj], 0, 0, 0); }

  // prologue: stage steps 0,1 of chunk 0
  STAGE(0, 0, 0);
  STAGE(1, 1, 0);

  int cbase = csplit + wc * 128;
#pragma unroll 1
  for (int c = 0; c < 8; ++c) {
    // steps 0..13: stage kk+2 of this chunk
#pragma unroll
    for (int kk = 0; kk < 14; ++kk) {
      STAGE(kk + 2, (kk + 2) & 3, 0);
      VMCNT10; BARRIER;
      COMPUTE(kk & 3);
      ZSTORE(c * 16 + kk);
    }
    // steps 14,15: stage next chunk's 0,1 (or drain on last chunk)
    if (c < 7) {
      STAGE(0, 0, 131072); VMCNT10; BARRIER; COMPUTE(2); ZSTORE(c * 16 + 14);
      STAGE(1, 1, 131072); VMCNT10; BARRIER; COMPUTE(3); ZSTORE(c * 16 + 15);
    } else {
      VMCNT5; BARRIER; COMPUTE(2); ZSTORE(c * 16 + 14);
      VMCNT0; BARRIER; COMPUTE(3); ZSTORE(c * 16 + 15);
    }

    // ---- chunk screening epilogue (runmax-margin) ----
    {
      float slotmax[8];
#pragma unroll
      for (int mi = 0; mi < 2; ++mi)
#pragma unroll
        for (int r = 0; r < 4; ++r) {
          float m = acc[mi][0][r];
#pragma unroll
          for (int nj = 1; nj < 8; ++nj) m = fmaxf(m, acc[mi][nj][r]);
          slotmax[mi * 4 + r] = m;
        }
#pragma unroll
      for (int d = 1; d < 16; d <<= 1)
#pragma unroll
        for (int sl = 0; sl < 8; ++sl)
          slotmax[sl] = fmaxf(slotmax[sl], __shfl_xor(slotmax[sl], d));
#pragma unroll
      for (int sl = 0; sl < 8; ++sl) runmax[sl] = fmaxf(runmax[sl], slotmax[sl]);
#pragma unroll
      for (int mi = 0; mi < 2; ++mi)
#pragma unroll
        for (int r = 0; r < 4; ++r) {
          const float th = runmax[mi * 4 + r] - MARGIN_AB;
          const int grow = row0 + wr * 32 + mi * 16 + rgrp + r;
#pragma unroll
          for (int nj = 0; nj < 8; ++nj) {
            const float ab = acc[mi][nj][r];
            if (ab > th) {
              const int cc = cbase + nj * 16 + arow;
              const int p = atomicAdd(&g_cnt[grow], 1);
              if (p < CAND_CAP) g_cand[(long)grow * CAND_CAP + p] = cc;
            }
            acc[mi][nj][r] = 0.0f;
          }
        }
    }
    // advance to next chunk
#pragma unroll
    for (int i = 0; i < 4; ++i) gB[i] += 131072;
    cbase += 256;
  }
#undef COMPUTE
#undef STAGE
#undef ZSTORE
}

// ---------------------------------------------------------------------------
// exact fp32 rescore (R2-proven) + fused per-token epilogue: enc scatter,
// quantized_st + m1 sum (exact R10 expression order), m2 sum using the raw
// latin row already held in registers.
__global__ __launch_bounds__(256) void k_rescore(const float* __restrict__ latin,
                                                 const float* __restrict__ inv_a,
                                                 const float* __restrict__ a2,
                                                 const float* __restrict__ latcb,
                                                 const float* __restrict__ inv_b,
                                                 const float* __restrict__ b2,
                                                 const int* __restrict__ g_cnt,
                                                 const int* __restrict__ g_cand,
                                                 const float* __restrict__ x,
                                                 const float* __restrict__ cb,
                                                 float* __restrict__ outq,
                                                 int* __restrict__ idxb,
                                                 float* __restrict__ out_idx,
                                                 float* __restrict__ enc,
                                                 int* __restrict__ hist,
                                                 float* __restrict__ sums) {
  const int tid = threadIdx.x;
  const int lane = tid & 63;
  const int row = blockIdx.x * 4 + (tid >> 6);
  const float iva = inv_a[row];
  const float4 v0 = *(const float4*)&latin[(long)row * HDIM + lane * 8];
  const float4 v1 = *(const float4*)&latin[(long)row * HDIM + lane * 8 + 4];
  float na[8];
  na[0] = v0.x * iva; na[1] = v0.y * iva; na[2] = v0.z * iva; na[3] = v0.w * iva;
  na[4] = v1.x * iva; na[5] = v1.y * iva; na[6] = v1.z * iva; na[7] = v1.w * iva;
  const float a2r = a2[row];
  int cnt = g_cnt[row]; if (cnt > CAND_CAP) cnt = CAND_CAP;
  float best = 3.4e38f; int bestc = 0x7fffffff;
  for (int ci = 0; ci < cnt; ++ci) {
    const int c = g_cand[(long)row * CAND_CAP + ci];
    const float ivb = inv_b[c];
    const float4 w0 = *(const float4*)&latcb[(long)c * HDIM + lane * 8];
    const float4 w1 = *(const float4*)&latcb[(long)c * HDIM + lane * 8 + 4];
    float dot = 0.0f;
    dot = fmaf(na[0], w0.x * ivb, dot); dot = fmaf(na[1], w0.y * ivb, dot);
    dot = fmaf(na[2], w0.z * ivb, dot); dot = fmaf(na[3], w0.w * ivb, dot);
    dot = fmaf(na[4], w1.x * ivb, dot); dot = fmaf(na[5], w1.y * ivb, dot);
    dot = fmaf(na[6], w1.z * ivb, dot); dot = fmaf(na[7], w1.w * ivb, dot);
#pragma unroll
    for (int o = 32; o; o >>= 1) dot += __shfl_xor(dot, o);
    const float dist = (a2r - 2.0f * dot) + b2[c];
    if (dist < best || (dist == best && c < bestc)) { best = dist; bestc = c; }
  }
  if (lane == 0) {
    idxb[row] = bestc;
    out_idx[row] = (float)bestc;
    enc[(long)row * KCB + bestc] = 1.0f;
    atomicAdd(&hist[bestc], 1);
  }

  // ---- fused quantized_st + m1 (x/cb rows, 3 float4 per lane) ----
  const float4* xr  = (const float4*)&x[(long)row * DDIM];
  const float4* cbr = (const float4*)&cb[(long)bestc * DDIM];
  float s1 = 0.0f;
#pragma unroll
  for (int i = 0; i < 3; ++i) {
    const float4 xv = xr[lane + i * 64];
    const float4 qv = cbr[lane + i * 64];
    const float dx0 = qv.x - xv.x, dx1 = qv.y - xv.y, dx2 = qv.z - xv.z, dx3 = qv.w - xv.w;
    f32x4 o;
    o[0] = xv.x + dx0; o[1] = xv.y + dx1; o[2] = xv.z + dx2; o[3] = xv.w + dx3;
    __builtin_nontemporal_store(o, (f32x4*)&outq[(long)row * DDIM + (lane + i * 64) * 4]);
    s1 += dx0 * dx0 + dx1 * dx1 + dx2 * dx2 + dx3 * dx3;
  }
#pragma unroll
  for (int o = 32; o; o >>= 1) s1 += __shfl_xor(s1, o);

  // ---- fused m2 (latcb[bestc] row vs raw latin row in registers) ----
  const float4 lq0 = *(const float4*)&latcb[(long)bestc * HDIM + lane * 8];
  const float4 lq1 = *(const float4*)&latcb[(long)bestc * HDIM + lane * 8 + 4];
  const float e0 = lq0.x - v0.x, e1 = lq0.y - v0.y, e2 = lq0.z - v0.z, e3 = lq0.w - v0.w;
  const float e4 = lq1.x - v1.x, e5 = lq1.y - v1.y, e6 = lq1.z - v1.z, e7 = lq1.w - v1.w;
  float s2 = e0 * e0 + e1 * e1 + e2 * e2 + e3 * e3
           + e4 * e4 + e5 * e5 + e6 * e6 + e7 * e7;
#pragma unroll
  for (int o = 32; o; o >>= 1) s2 += __shfl_xor(s2, o);

  if (lane == 0) {
    atomicAdd(&sums[0], s1);
    atomicAdd(&sums[1], s2);
  }
}

// ---------------------------------------------------------------------------
__global__ __launch_bounds__(256) void k_finalize(const int* __restrict__ hist,
                                                  const float* __restrict__ sums,
                                                  float* __restrict__ out) {
  const int tid = threadIdx.x;
  float lsum = 0.0f;
  for (int i = tid; i < KCB; i += 256) {
    const float p = (float)hist[i] * (1.0f / 16384.0f);
    lsum += p * logf(p + 1e-6f);
  }
  __shared__ float red[256];
  red[tid] = lsum; __syncthreads();
  for (int s = 128; s; s >>= 1) { if (tid < s) red[tid] += red[tid + s]; __syncthreads(); }
  if (tid == 0) {
    const float lp = -red[0];
    const float m1 = sums[0] / 12582912.0f;
    const float m2 = sums[1] / 8388608.0f;
    out[LOSS_OFF] = m1 * 1.25f + m2 * 1.25f + 0.1f * lp;
    out[PERP_OFF] = expf(lp);
  }
}

// ---------------------------------------------------------------------------
extern "C" void kernel_launch(void* const* d_in, const int* in_sizes, int n_in,
                              void* d_out, int out_size, void* d_ws, size_t ws_size,
                              hipStream_t stream) {
  const float* x      = (const float*)d_in[0];
  const float* cb     = (const float*)d_in[1];
  const float* w_in   = (const float*)d_in[2];
  const float* b_in   = (const float*)d_in[3];
  const float* w_code = (const float*)d_in[4];
  const float* b_code = (const float*)d_in[5];
  float* out = (float*)d_out;
  char* ws = (char*)d_ws;

  float*          latcb    = (float*)(ws);                      // 8 MB
  float*          latin    = (float*)(ws + 8388608);            // 32 MB
  _Float16*       x2       = (_Float16*)(ws + 41943040);        // 48 MB [hi|lo]
  _Float16*       cb2      = (_Float16*)(ws + 92274688);        // 12.6 MB
  _Float16*       win2     = (_Float16*)(ws + 104857600);       // 1.5 MB
  _Float16*       wcode2   = (_Float16*)(ws + 106430464);       // 1.5 MB
  float*          inv_b    = (float*)(ws + 108003328);
  float*          b2       = (float*)(ws + 108019712);
  float*          inv_a    = (float*)(ws + 108036096);
  float*          a2       = (float*)(ws + 108101632);
  int*            idxb     = (int*)  (ws + 108167168);
  int*            hist     = (int*)  (ws + 108232704);
  float*          sums     = (float*)(ws + 108249088);
  int*            g_cnt    = (int*)  (ws + 108249120);
  // reuse of x2/cb2/win2/wcode2 region after k_hgemm:
  unsigned short* latin_bf = (unsigned short*)(ws + 41943040);  // 16 MB
  unsigned short* latcb_bf = (unsigned short*)(ws + 58720256);  // 4 MB
  int*            g_cand   = (int*)  (ws + 62914560);           // 8 MB

  const long prep_groups = (long)(N_TOK + KCB + 512 + 512) * 96;   // 2064384
  k_prep<<<(int)((prep_groups + 255) / 256), 256, 0, stream>>>(
      x, cb, w_in, w_code, x2, cb2, win2, wcode2, hist, sums, g_cnt);
  k_hgemm<<<dim3(128 + KCB / BMT, HDIM / BNT), 256, 0, stream>>>(x2, cb2, win2, wcode2,
                                                                 b_in, b_code, latin, latcb);
  k_rownorm2<<<(KCB + N_TOK) / 4, 256, 0, stream>>>(latcb, latin, inv_b, b2, inv_a, a2,
                                                    latcb_bf, latin_bf);
  k_screen<<<dim3(N_TOK / 64, KCB / CODES_PER), 256, 0, stream>>>(latin_bf, latcb_bf,
                                                                  g_cnt, g_cand,
                                                                  (f32x4*)(out + ENC_OFF));
  k_rescore<<<N_TOK / 4, 256, 0, stream>>>(latin, inv_a, a2, latcb, inv_b, b2,
                                           g_cnt, g_cand, x, cb, out + Q_OFF,
                                           idxb, out + IDX_OFF, out + ENC_OFF,
                                           hist, sums);
  k_finalize<<<1, 256, 0, stream>>>(hist, sums, out);
}

// Round 19
// 410.464 us; speedup vs baseline: 1.8954x; 1.8954x over previous
//
#include <hip/hip_runtime.h>
#include <math.h>

// Problem constants
#define N_TOK 16384   // B*S
#define DDIM  768
#define HDIM  512
#define KCB   4096

// d_out float offsets (outputs concatenated: quantized_st, loss, perplexity, idx, enc)
#define Q_OFF    0L
#define LOSS_OFF 12582912L
#define PERP_OFF 12582913L
#define IDX_OFF  12582914L
#define ENC_OFF  12599298L

#define MARGIN_AB 4.0e-3f   // hard bound: bf16 rel err 2^-9 -> dot err <= 2*2^-9 = 3.9e-3
#define CAND_CAP 128

// screen geometry (R10-proven): BM=64 rows, 2048 codes/block (8 chunks x 256), BK=32
#define CODES_PER 2048

// hgemm (R5-proven): 128x128 tile, BK=32. K' = 2304 virtual (Ah@Wh | Al@Wh | Ah@Wl)
#define BMT 128
#define BNT 128
#define KS 1536
#define HSTEPS (2304 / 32)   // 72

typedef short    bf16x8 __attribute__((ext_vector_type(8)));
typedef _Float16 half8  __attribute__((ext_vector_type(8)));
typedef float    f32x4  __attribute__((ext_vector_type(4)));

__device__ __forceinline__ void gload_lds16(const void* g, void* l) {
  __builtin_amdgcn_global_load_lds((const __attribute__((address_space(1))) void*)g,
                                   (__attribute__((address_space(3))) void*)l, 16, 0, 0);
}

__device__ __forceinline__ unsigned short f2bf(float f) {  // RNE f32 -> bf16
  unsigned u = __float_as_uint(f);
  return (unsigned short)((u + 0x7fffu + ((u >> 16) & 1u)) >> 16);
}

#define VMCNT10 asm volatile("s_waitcnt vmcnt(10)" ::: "memory")
#define VMCNT5  asm volatile("s_waitcnt vmcnt(5)" ::: "memory")
#define VMCNT0  asm volatile("s_waitcnt vmcnt(0)" ::: "memory")
#define BARRIER asm volatile("s_barrier" ::: "memory")

// ---------------------------------------------------------------------------
// fused prep: init + all 4 hi/lo splits (R12-proven).
__global__ __launch_bounds__(256) void k_prep(const float* __restrict__ x,
                                              const float* __restrict__ cb,
                                              const float* __restrict__ w_in,
                                              const float* __restrict__ w_code,
                                              _Float16* __restrict__ x2,
                                              _Float16* __restrict__ cb2,
                                              _Float16* __restrict__ win2,
                                              _Float16* __restrict__ wcode2,
                                              int* __restrict__ hist,
                                              int* __restrict__ g_cnt) {
  const long u = (long)blockIdx.x * 256 + threadIdx.x;
  if (u < 16448) {  // init lane
    const int g = (int)u;
    if (g < N_TOK) g_cnt[g] = 0;
    if (g < KCB)  hist[g] = 0;
  }
  const float* src; _Float16* dst; long n;
  long v = u;
  if (v < (long)N_TOK * 96)                           { src = x;      dst = x2;     n = v / 96; }
  else if ((v -= (long)N_TOK * 96) < (long)KCB * 96)  { src = cb;     dst = cb2;    n = v / 96; }
  else if ((v -= (long)KCB * 96) < 512L * 96)         { src = w_in;   dst = win2;   n = v / 96; }
  else if ((v -= 512L * 96) < 512L * 96)              { src = w_code; dst = wcode2; n = v / 96; }
  else return;
  const int c0 = ((int)(v % 96)) * 8;
  const float4 v0 = *(const float4*)&src[n * DDIM + c0];
  const float4 v1 = *(const float4*)&src[n * DDIM + c0 + 4];
  const float f[8] = {v0.x, v0.y, v0.z, v0.w, v1.x, v1.y, v1.z, v1.w};
  half8 hv, lv;
#pragma unroll
  for (int j = 0; j < 8; ++j) {
    const _Float16 h = (_Float16)f[j];
    hv[j] = h;
    lv[j] = (_Float16)(f[j] - (float)h);
  }
  *(half8*)&dst[n * KS + c0]       = hv;
  *(half8*)&dst[n * KS + 768 + c0] = lv;
}

// ---------------------------------------------------------------------------
// fp16 split MFMA GEMM (R5-proven): 128x128 tile, BK=32, dbuf linear LDS.
// bx < 128 -> x rows; else codebook rows.
__global__ __launch_bounds__(256) void k_hgemm(const _Float16* __restrict__ x2,
                                               const _Float16* __restrict__ cb2,
                                               const _Float16* __restrict__ win2,
                                               const _Float16* __restrict__ wcode2,
                                               const float* __restrict__ b_in,
                                               const float* __restrict__ b_code,
                                               float* __restrict__ latin,
                                               float* __restrict__ latcb) {
  __shared__ __align__(16) _Float16 A_lds[2][BMT][32];
  __shared__ __align__(16) _Float16 B_lds[2][BNT][32];

  const int tid = threadIdx.x;
  const int lane = tid & 63;
  const int w = tid >> 6;
  const int wr = w >> 1, wc = w & 1;   // wave quadrant: 64x64
  const int arow = lane & 15;
  const int kseg = lane >> 4;          // 0..3
  const int rgrp = (lane >> 4) * 4;
  const int bx = blockIdx.x;
  const int col0 = blockIdx.y * BNT;

  const _Float16* Ap; const float* biasp; float* outp; int row0;
  if (bx < 128) { Ap = x2;  biasp = b_in;   outp = latin; row0 = bx * BMT; }
  else          { Ap = cb2; biasp = b_code; outp = latcb; row0 = (bx - 128) * BMT; }
  const _Float16* Bp = (bx < 128) ? win2 : wcode2;

  f32x4 acc[4][4];
#pragma unroll
  for (int mi = 0; mi < 4; ++mi)
#pragma unroll
    for (int nj = 0; nj < 4; ++nj)
#pragma unroll
      for (int r = 0; r < 4; ++r) acc[mi][nj][r] = 0.0f;

#define HSTAGE(s_, b_)                                                         \
  do {                                                                         \
    const int kel_ = (s_) * 32;                                                \
    const int kA_ = (kel_ < KS) ? kel_ : (kel_ - KS);                          \
    const int kB_ = (kel_ < 768) ? kel_ : (kel_ - 768);                        \
    _Pragma("unroll")                                                          \
    for (int i_ = 0; i_ < 2; ++i_) {                                           \
      const int v_ = tid + i_ * 256;                                           \
      const int r_ = v_ >> 2, sg_ = v_ & 3;                                    \
      gload_lds16(&Ap[(long)(row0 + r_) * KS + kA_ + sg_ * 8],                 \
                  (char*)&A_lds[b_][0][0] + (size_t)v_ * 16);                  \
    }                                                                          \
    _Pragma("unroll")                                                          \
    for (int i_ = 0; i_ < 2; ++i_) {                                           \
      const int v_ = tid + i_ * 256;                                           \
      const int r_ = v_ >> 2, sg_ = v_ & 3;                                    \
      gload_lds16(&Bp[(long)(col0 + r_) * KS + kB_ + sg_ * 8],                 \
                  (char*)&B_lds[b_][0][0] + (size_t)v_ * 16);                  \
    }                                                                          \
  } while (0)

  HSTAGE(0, 0);
  __syncthreads();

  for (int s = 0; s < HSTEPS; ++s) {
    const int b = s & 1;
    if (s + 1 < HSTEPS) HSTAGE(s + 1, b ^ 1);
    half8 af[4], bfr[4];
#pragma unroll
    for (int mi = 0; mi < 4; ++mi)
      af[mi] = *(const half8*)&A_lds[b][wr * 64 + mi * 16 + arow][kseg * 8];
#pragma unroll
    for (int nj = 0; nj < 4; ++nj)
      bfr[nj] = *(const half8*)&B_lds[b][wc * 64 + nj * 16 + arow][kseg * 8];
#pragma unroll
    for (int mi = 0; mi < 4; ++mi)
#pragma unroll
      for (int nj = 0; nj < 4; ++nj)
        acc[mi][nj] = __builtin_amdgcn_mfma_f32_16x16x32_f16(af[mi], bfr[nj], acc[mi][nj], 0, 0, 0);
    __syncthreads();
  }
#undef HSTAGE

#pragma unroll
  for (int nj = 0; nj < 4; ++nj) {
    const int ocol = col0 + wc * 64 + nj * 16 + arow;
    const float bv = biasp[ocol];
#pragma unroll
    for (int mi = 0; mi < 4; ++mi)
#pragma unroll
      for (int r = 0; r < 4; ++r) {
        const int orow = row0 + wr * 64 + mi * 16 + rgrp + r;
        outp[(long)orow * HDIM + ocol] = acc[mi][nj][r] + bv;
      }
  }
}

// ---------------------------------------------------------------------------
// fused rownorm (R12-proven): 4 rows/block. row < 4096 -> latcb, else latin.
__global__ __launch_bounds__(256) void k_rownorm2(const float* __restrict__ latcb,
                                                  const float* __restrict__ latin,
                                                  float* __restrict__ inv_b,
                                                  float* __restrict__ b2,
                                                  float* __restrict__ inv_a,
                                                  float* __restrict__ a2,
                                                  unsigned short* __restrict__ latcb_bf,
                                                  unsigned short* __restrict__ latin_bf) {
  const int grow = blockIdx.x * 4 + (threadIdx.x >> 6);
  const int lane = threadIdx.x & 63;
  const float* raw; float* inv; float* n2; unsigned short* nbf; int row;
  if (grow < KCB) { raw = latcb; inv = inv_b; n2 = b2; nbf = latcb_bf; row = grow; }
  else            { raw = latin; inv = inv_a; n2 = a2; nbf = latin_bf; row = grow - KCB; }
  const float4 v0 = *(const float4*)&raw[(long)row * HDIM + lane * 8];
  const float4 v1 = *(const float4*)&raw[(long)row * HDIM + lane * 8 + 4];
  float s = v0.x * v0.x + v0.y * v0.y + v0.z * v0.z + v0.w * v0.w
          + v1.x * v1.x + v1.y * v1.y + v1.z * v1.z + v1.w * v1.w;
#pragma unroll
  for (int o = 32; o; o >>= 1) s += __shfl_xor(s, o);
  const float iv = 1.0f / sqrtf(s + 1e-6f);
  float t[8];
  t[0] = v0.x * iv; t[1] = v0.y * iv; t[2] = v0.z * iv; t[3] = v0.w * iv;
  t[4] = v1.x * iv; t[5] = v1.y * iv; t[6] = v1.z * iv; t[7] = v1.w * iv;
  float s2 = 0.0f;
#pragma unroll
  for (int j = 0; j < 8; ++j) s2 += t[j] * t[j];
#pragma unroll
  for (int o = 32; o; o >>= 1) s2 += __shfl_xor(s2, o);
  bf16x8 pk;
#pragma unroll
  for (int j = 0; j < 8; ++j) pk[j] = (short)f2bf(t[j]);
  *(bf16x8*)&nbf[(long)row * HDIM + lane * 8] = pk;
  if (lane == 0) { inv[row] = iv; n2[row] = s2; }
}

// ---------------------------------------------------------------------------
// bf16 MFMA screening (R17-proven): R10 schedule + fused enc zero-fill
// (one nt-store per thread per K-step, hidden under the MFMA pipeline).
__global__ __launch_bounds__(256) void k_screen(const unsigned short* __restrict__ Abf,
                                                const unsigned short* __restrict__ Bbf,
                                                int* __restrict__ g_cnt,
                                                int* __restrict__ g_cand,
                                                f32x4* __restrict__ encz) {
  __shared__ __align__(16) unsigned short A_lds[4][64][32];    // 16 KB
  __shared__ __align__(16) unsigned short B_lds[4][256][32];   // 64 KB

  const int tid = threadIdx.x;
  const int lane = tid & 63;
  const int w = tid >> 6;
  const int wr = w >> 1, wc = w & 1;   // wave tile: 32 rows x 128 codes
  const int arow = lane & 15;
  const int kseg = lane >> 4;          // 0..3
  const int rgrp = kseg * 4;
  const int row0 = blockIdx.x * 64;
  const int csplit = blockIdx.y * CODES_PER;

  // enc zero-fill slice: flat block id * 32768 f32x4 (512KB), 256/step
  f32x4* encp = encz + ((long)(blockIdx.y * (N_TOK / 64) + blockIdx.x)) * 32768 + tid;
  const f32x4 z4 = {0.0f, 0.0f, 0.0f, 0.0f};
#define ZSTORE(sid_) __builtin_nontemporal_store(z4, encp + (sid_) * 256)

  // staging source pointers (seg pre-swizzled: seg_g = seg ^ ((row>>1)&3))
  const int ar = tid >> 2;
  const int aseg = (tid & 3) ^ ((ar >> 1) & 3);
  const unsigned short* gA = Abf + (long)(row0 + ar) * HDIM + aseg * 8;
  const unsigned short* gB[4];
#pragma unroll
  for (int i = 0; i < 4; ++i) {
    const int u = tid + i * 256;
    const int br = u >> 2;
    const int bseg = (u & 3) ^ ((br >> 1) & 3);
    gB[i] = Bbf + (long)(csplit + br) * HDIM + bseg * 8;
  }

  // swizzled LDS frag-read base pointers
  const int q = (arow >> 1) & 3;
  const int ss = (kseg ^ q) * 16;
  const char* pAf = (const char*)&A_lds[0][0][0] + (wr * 32 + arow) * 64 + ss;
  const char* pBf = (const char*)&B_lds[0][0][0] + (wc * 128 + arow) * 64 + ss;

  f32x4 acc[2][8];
#pragma unroll
  for (int mi = 0; mi < 2; ++mi)
#pragma unroll
    for (int nj = 0; nj < 8; ++nj)
#pragma unroll
      for (int r = 0; r < 4; ++r) acc[mi][nj][r] = 0.0f;

  float runmax[8];
#pragma unroll
  for (int i = 0; i < 8; ++i) runmax[i] = -3.0e38f;

#define STAGE(kk_, buf_, CADD_)                                                \
  { gload_lds16(gA + (kk_) * 32,                                               \
                (char*)&A_lds[0][0][0] + (buf_) * 4096 + (size_t)tid * 16);    \
    _Pragma("unroll")                                                          \
    for (int i_ = 0; i_ < 4; ++i_)                                             \
      gload_lds16(gB[i_] + (CADD_) + (kk_) * 32,                               \
                  (char*)&B_lds[0][0][0] + (buf_) * 16384 +                    \
                  (size_t)(tid + i_ * 256) * 16); }

#define COMPUTE(buf_)                                                          \
  { bf16x8 af[2], bfr[8];                                                      \
    af[0] = *(const bf16x8*)(pAf + (buf_) * 4096);                             \
    af[1] = *(const bf16x8*)(pAf + (buf_) * 4096 + 1024);                      \
    _Pragma("unroll")                                                          \
    for (int nj = 0; nj < 8; ++nj)                                             \
      bfr[nj] = *(const bf16x8*)(pBf + (buf_) * 16384 + nj * 1024);            \
    _Pragma("unroll")                                                          \
    for (int mi = 0; mi < 2; ++mi)                                             \
      _Pragma("unroll")                                                        \
      for (int nj = 0; nj < 8; ++nj)                                           \
        acc[mi][nj] = __builtin_amdgcn_mfma_f32_16x16x32_bf16(af[mi], bfr[nj], \
                                                              acc[mi][nj], 0, 0, 0); }

  // prologue: stage steps 0,1 of chunk 0
  STAGE(0, 0, 0);
  STAGE(1, 1, 0);

  int cbase = csplit + wc * 128;
#pragma unroll 1
  for (int c = 0; c < 8; ++c) {
    // steps 0..13: stage kk+2 of this chunk
#pragma unroll
    for (int kk = 0; kk < 14; ++kk) {
      STAGE(kk + 2, (kk + 2) & 3, 0);
      VMCNT10; BARRIER;
      COMPUTE(kk & 3);
      ZSTORE(c * 16 + kk);
    }
    // steps 14,15: stage next chunk's 0,1 (or drain on last chunk)
    if (c < 7) {
      STAGE(0, 0, 131072); VMCNT10; BARRIER; COMPUTE(2); ZSTORE(c * 16 + 14);
      STAGE(1, 1, 131072); VMCNT10; BARRIER; COMPUTE(3); ZSTORE(c * 16 + 15);
    } else {
      VMCNT5; BARRIER; COMPUTE(2); ZSTORE(c * 16 + 14);
      VMCNT0; BARRIER; COMPUTE(3); ZSTORE(c * 16 + 15);
    }

    // ---- chunk screening epilogue (runmax-margin) ----
    {
      float slotmax[8];
#pragma unroll
      for (int mi = 0; mi < 2; ++mi)
#pragma unroll
        for (int r = 0; r < 4; ++r) {
          float m = acc[mi][0][r];
#pragma unroll
          for (int nj = 1; nj < 8; ++nj) m = fmaxf(m, acc[mi][nj][r]);
          slotmax[mi * 4 + r] = m;
        }
#pragma unroll
      for (int d = 1; d < 16; d <<= 1)
#pragma unroll
        for (int sl = 0; sl < 8; ++sl)
          slotmax[sl] = fmaxf(slotmax[sl], __shfl_xor(slotmax[sl], d));
#pragma unroll
      for (int sl = 0; sl < 8; ++sl) runmax[sl] = fmaxf(runmax[sl], slotmax[sl]);
#pragma unroll
      for (int mi = 0; mi < 2; ++mi)
#pragma unroll
        for (int r = 0; r < 4; ++r) {
          const float th = runmax[mi * 4 + r] - MARGIN_AB;
          const int grow = row0 + wr * 32 + mi * 16 + rgrp + r;
#pragma unroll
          for (int nj = 0; nj < 8; ++nj) {
            const float ab = acc[mi][nj][r];
            if (ab > th) {
              const int cc = cbase + nj * 16 + arow;
              const int p = atomicAdd(&g_cnt[grow], 1);
              if (p < CAND_CAP) g_cand[(long)grow * CAND_CAP + p] = cc;
            }
            acc[mi][nj][r] = 0.0f;
          }
        }
    }
    // advance to next chunk
#pragma unroll
    for (int i = 0; i < 4; ++i) gB[i] += 131072;
    cbase += 256;
  }
#undef COMPUTE
#undef STAGE
#undef ZSTORE
}

// ---------------------------------------------------------------------------
// exact fp32 rescore (R2-proven) + fused per-token epilogue (R18) with the
// atomic fix: per-block LDS reduction -> per-block partials (no contended
// atomics); k_finalize sums the partials deterministically.
__global__ __launch_bounds__(256) void k_rescore(const float* __restrict__ latin,
                                                 const float* __restrict__ inv_a,
                                                 const float* __restrict__ a2,
                                                 const float* __restrict__ latcb,
                                                 const float* __restrict__ inv_b,
                                                 const float* __restrict__ b2,
                                                 const int* __restrict__ g_cnt,
                                                 const int* __restrict__ g_cand,
                                                 const float* __restrict__ x,
                                                 const float* __restrict__ cb,
                                                 float* __restrict__ outq,
                                                 int* __restrict__ idxb,
                                                 float* __restrict__ out_idx,
                                                 float* __restrict__ enc,
                                                 int* __restrict__ hist,
                                                 float* __restrict__ partials) {
  const int tid = threadIdx.x;
  const int lane = tid & 63;
  const int wid = tid >> 6;
  const int row = blockIdx.x * 4 + wid;
  const float iva = inv_a[row];
  const float4 v0 = *(const float4*)&latin[(long)row * HDIM + lane * 8];
  const float4 v1 = *(const float4*)&latin[(long)row * HDIM + lane * 8 + 4];
  float na[8];
  na[0] = v0.x * iva; na[1] = v0.y * iva; na[2] = v0.z * iva; na[3] = v0.w * iva;
  na[4] = v1.x * iva; na[5] = v1.y * iva; na[6] = v1.z * iva; na[7] = v1.w * iva;
  const float a2r = a2[row];
  int cnt = g_cnt[row]; if (cnt > CAND_CAP) cnt = CAND_CAP;
  float best = 3.4e38f; int bestc = 0x7fffffff;
  for (int ci = 0; ci < cnt; ++ci) {
    const int c = g_cand[(long)row * CAND_CAP + ci];
    const float ivb = inv_b[c];
    const float4 w0 = *(const float4*)&latcb[(long)c * HDIM + lane * 8];
    const float4 w1 = *(const float4*)&latcb[(long)c * HDIM + lane * 8 + 4];
    float dot = 0.0f;
    dot = fmaf(na[0], w0.x * ivb, dot); dot = fmaf(na[1], w0.y * ivb, dot);
    dot = fmaf(na[2], w0.z * ivb, dot); dot = fmaf(na[3], w0.w * ivb, dot);
    dot = fmaf(na[4], w1.x * ivb, dot); dot = fmaf(na[5], w1.y * ivb, dot);
    dot = fmaf(na[6], w1.z * ivb, dot); dot = fmaf(na[7], w1.w * ivb, dot);
#pragma unroll
    for (int o = 32; o; o >>= 1) dot += __shfl_xor(dot, o);
    const float dist = (a2r - 2.0f * dot) + b2[c];
    if (dist < best || (dist == best && c < bestc)) { best = dist; bestc = c; }
  }
  if (lane == 0) {
    idxb[row] = bestc;
    out_idx[row] = (float)bestc;
    enc[(long)row * KCB + bestc] = 1.0f;
    atomicAdd(&hist[bestc], 1);
  }

  // ---- fused quantized_st + m1 (x/cb rows, 3 float4 per lane) ----
  const float4* xr  = (const float4*)&x[(long)row * DDIM];
  const float4* cbr = (const float4*)&cb[(long)bestc * DDIM];
  float s1 = 0.0f;
#pragma unroll
  for (int i = 0; i < 3; ++i) {
    const float4 xv = xr[lane + i * 64];
    const float4 qv = cbr[lane + i * 64];
    const float dx0 = qv.x - xv.x, dx1 = qv.y - xv.y, dx2 = qv.z - xv.z, dx3 = qv.w - xv.w;
    f32x4 o;
    o[0] = xv.x + dx0; o[1] = xv.y + dx1; o[2] = xv.z + dx2; o[3] = xv.w + dx3;
    __builtin_nontemporal_store(o, (f32x4*)&outq[(long)row * DDIM + (lane + i * 64) * 4]);
    s1 += dx0 * dx0 + dx1 * dx1 + dx2 * dx2 + dx3 * dx3;
  }
#pragma unroll
  for (int o = 32; o; o >>= 1) s1 += __shfl_xor(s1, o);

  // ---- fused m2 (latcb[bestc] row vs raw latin row in registers) ----
  const float4 lq0 = *(const float4*)&latcb[(long)bestc * HDIM + lane * 8];
  const float4 lq1 = *(const float4*)&latcb[(long)bestc * HDIM + lane * 8 + 4];
  const float e0 = lq0.x - v0.x, e1 = lq0.y - v0.y, e2 = lq0.z - v0.z, e3 = lq0.w - v0.w;
  const float e4 = lq1.x - v1.x, e5 = lq1.y - v1.y, e6 = lq1.z - v1.z, e7 = lq1.w - v1.w;
  float s2 = e0 * e0 + e1 * e1 + e2 * e2 + e3 * e3
           + e4 * e4 + e5 * e5 + e6 * e6 + e7 * e7;
#pragma unroll
  for (int o = 32; o; o >>= 1) s2 += __shfl_xor(s2, o);

  // ---- block reduction to per-block partials (no contended atomics) ----
  __shared__ float red1[4];
  __shared__ float red2[4];
  if (lane == 0) { red1[wid] = s1; red2[wid] = s2; }
  __syncthreads();
  if (tid == 0) {
    partials[blockIdx.x * 2]     = red1[0] + red1[1] + red1[2] + red1[3];
    partials[blockIdx.x * 2 + 1] = red2[0] + red2[1] + red2[2] + red2[3];
  }
}

// ---------------------------------------------------------------------------
__global__ __launch_bounds__(256) void k_finalize(const int* __restrict__ hist,
                                                  const float* __restrict__ partials,
                                                  float* __restrict__ out) {
  const int tid = threadIdx.x;
  float lsum = 0.0f;
  for (int i = tid; i < KCB; i += 256) {
    const float p = (float)hist[i] * (1.0f / 16384.0f);
    lsum += p * logf(p + 1e-6f);
  }
  float p1 = 0.0f, p2 = 0.0f;
  for (int i = tid; i < N_TOK / 4; i += 256) {
    p1 += partials[i * 2];
    p2 += partials[i * 2 + 1];
  }
  __shared__ float red[256], redA[256], redB[256];
  red[tid] = lsum; redA[tid] = p1; redB[tid] = p2;
  __syncthreads();
  for (int s = 128; s; s >>= 1) {
    if (tid < s) { red[tid] += red[tid + s]; redA[tid] += redA[tid + s]; redB[tid] += redB[tid + s]; }
    __syncthreads();
  }
  if (tid == 0) {
    const float lp = -red[0];
    const float m1 = redA[0] / 12582912.0f;
    const float m2 = redB[0] / 8388608.0f;
    out[LOSS_OFF] = m1 * 1.25f + m2 * 1.25f + 0.1f * lp;
    out[PERP_OFF] = expf(lp);
  }
}

// ---------------------------------------------------------------------------
extern "C" void kernel_launch(void* const* d_in, const int* in_sizes, int n_in,
                              void* d_out, int out_size, void* d_ws, size_t ws_size,
                              hipStream_t stream) {
  const float* x      = (const float*)d_in[0];
  const float* cb     = (const float*)d_in[1];
  const float* w_in   = (const float*)d_in[2];
  const float* b_in   = (const float*)d_in[3];
  const float* w_code = (const float*)d_in[4];
  const float* b_code = (const float*)d_in[5];
  float* out = (float*)d_out;
  char* ws = (char*)d_ws;

  float*          latcb    = (float*)(ws);                      // 8 MB
  float*          latin    = (float*)(ws + 8388608);            // 32 MB
  _Float16*       x2       = (_Float16*)(ws + 41943040);        // 48 MB [hi|lo]
  _Float16*       cb2      = (_Float16*)(ws + 92274688);        // 12.6 MB
  _Float16*       win2     = (_Float16*)(ws + 104857600);       // 1.5 MB
  _Float16*       wcode2   = (_Float16*)(ws + 106430464);       // 1.5 MB
  float*          inv_b    = (float*)(ws + 108003328);
  float*          b2       = (float*)(ws + 108019712);
  float*          inv_a    = (float*)(ws + 108036096);
  float*          a2       = (float*)(ws + 108101632);
  int*            idxb     = (int*)  (ws + 108167168);
  int*            hist     = (int*)  (ws + 108232704);
  float*          partials = (float*)(ws + 108249088);          // 4096*2 f32 (32 KB)
  int*            g_cnt    = (int*)  (ws + 108282048);
  // reuse of x2/cb2/win2/wcode2 region after k_hgemm:
  unsigned short* latin_bf = (unsigned short*)(ws + 41943040);  // 16 MB
  unsigned short* latcb_bf = (unsigned short*)(ws + 58720256);  // 4 MB
  int*            g_cand   = (int*)  (ws + 62914560);           // 8 MB

  const long prep_groups = (long)(N_TOK + KCB + 512 + 512) * 96;   // 2064384
  k_prep<<<(int)((prep_groups + 255) / 256), 256, 0, stream>>>(
      x, cb, w_in, w_code, x2, cb2, win2, wcode2, hist, g_cnt);
  k_hgemm<<<dim3(128 + KCB / BMT, HDIM / BNT), 256, 0, stream>>>(x2, cb2, win2, wcode2,
                                                                 b_in, b_code, latin, latcb);
  k_rownorm2<<<(KCB + N_TOK) / 4, 256, 0, stream>>>(latcb, latin, inv_b, b2, inv_a, a2,
                                                    latcb_bf, latin_bf);
  k_screen<<<dim3(N_TOK / 64, KCB / CODES_PER), 256, 0, stream>>>(latin_bf, latcb_bf,
                                                                  g_cnt, g_cand,
                                                                  (f32x4*)(out + ENC_OFF));
  k_rescore<<<N_TOK / 4, 256, 0, stream>>>(latin, inv_a, a2, latcb, inv_b, b2,
                                           g_cnt, g_cand, x, cb, out + Q_OFF,
                                           idxb, out + IDX_OFF, out + ENC_OFF,
                                           hist, partials);
  k_finalize<<<1, 256, 0, stream>>>(hist, partials, out);
}